// Round 9
// baseline (155.070 us; speedup 1.0000x reference)
//
#include <hip/hip_runtime.h>
#include <hip/hip_bf16.h>
#include <math.h>

#define N_TOT 8192
#define HALF_N 4096
#define D_DIM 512
#define BM 128
#define NKB 8          // 8 k-blocks of 64 bytes each (K=512 fp8)
#define NTILES 2080    // 64*65/2 upper-triangle 128x128 tiles

typedef float f32x4_t __attribute__((ext_vector_type(4)));
typedef long long i64x2 __attribute__((ext_vector_type(2)));

// Kernel 1: L2-normalize rows of [p1;p2] -> fp8 e4m3 Z in k-PERMUTED layout;
// zero rowsum + out. Permutation (within each 64B k-block): byte for k-piece
// (h = k5, q = k43, half = k2) stored at b*64 + q*16 + h*8 + half*4. Both A
// and B panels use the same bijection, so GEMM dot products are unaffected.
__global__ __launch_bounds__(256) void k_normalize(
    const float* __restrict__ p1, const float* __restrict__ p2,
    unsigned char* __restrict__ zf8, float* __restrict__ rowsum,
    float* __restrict__ out)
{
    const int w = threadIdx.x >> 6;
    const int lane = threadIdx.x & 63;
    const int row = blockIdx.x * 4 + w;

    if (threadIdx.x < 4) rowsum[blockIdx.x * 4 + threadIdx.x] = 0.0f;
    if (blockIdx.x == 0 && threadIdx.x == 0) out[0] = 0.0f;

    const float* src = (row < HALF_N) ? p1 + (size_t)row * D_DIM
                                      : p2 + (size_t)(row - HALF_N) * D_DIM;
    float4 a = *(const float4*)(src + lane * 4);
    float4 b = *(const float4*)(src + 256 + lane * 4);
    float s = a.x*a.x + a.y*a.y + a.z*a.z + a.w*a.w
            + b.x*b.x + b.y*b.y + b.z*b.z + b.w*b.w;
    #pragma unroll
    for (int m = 1; m < 64; m <<= 1) s += __shfl_xor(s, m, 64);
    float inv = 1.0f / fmaxf(sqrtf(s), 1e-8f);

    int pk0 = __builtin_amdgcn_cvt_pk_fp8_f32(a.x * inv, a.y * inv, 0, false);
    pk0     = __builtin_amdgcn_cvt_pk_fp8_f32(a.z * inv, a.w * inv, pk0, true);
    int pk1 = __builtin_amdgcn_cvt_pk_fp8_f32(b.x * inv, b.y * inv, 0, false);
    pk1     = __builtin_amdgcn_cvt_pk_fp8_f32(b.z * inv, b.w * inv, pk1, true);

    unsigned char* dst = zf8 + (size_t)row * D_DIM;
    // int at original k-offset o -> permuted offset
    const int o0 = lane * 4;
    const int o1 = 256 + lane * 4;
    const int d0 = (o0 & ~63) + ((o0 >> 3) & 3) * 16 + ((o0 >> 5) & 1) * 8 + ((o0 >> 2) & 1) * 4;
    const int d1 = (o1 & ~63) + ((o1 >> 3) & 3) * 16 + ((o1 >> 5) & 1) * 8 + ((o1 >> 2) & 1) * 4;
    *(int*)(dst + d0) = pk0;
    *(int*)(dst + d1) = pk1;
}

// Kernel 2: upper-triangle tiles of sim = Z*Z^T via fp8 MFMA 16x16x32.
// NO LDS, NO barriers in the K-loop: fragments load global->VGPR (b128/lane,
// k-permuted Z makes each lane's two 8B MFMA pieces contiguous). Manual
// 2-stage pipeline; compiler pipelines with vmcnt(N), never vmcnt(0).
__global__ __launch_bounds__(256) void k_gemm(
    const unsigned char* __restrict__ zf8,
    float* __restrict__ rowsum, float* __restrict__ pos)
{
    const int tid = threadIdx.x;
    const int lane = tid & 63;
    const int w = tid >> 6;
    const int wr = w >> 1, wc = w & 1;
    const int q = lane >> 4, l15 = lane & 15;

    // triangular block mapping: t -> (bx >= by)
    const int t = blockIdx.x;
    int bi = (int)((sqrtf(8.0f * (float)t + 1.0f) - 1.0f) * 0.5f);
    while ((bi + 1) * (bi + 2) / 2 <= t) ++bi;
    while (bi * (bi + 1) / 2 > t) --bi;
    const int bx = bi;                       // col tile (larger)
    const int by = t - bi * (bi + 1) / 2;    // row tile
    const bool isDiag = (bx == by);
    const bool hasPos = (bx - by == 32);
    const int rowBase = by * BM;
    const int colBase = bx * BM;

    // per-lane fragment base pointers (k-block 0)
    const unsigned char* aP[4];
    const unsigned char* bP[4];
    #pragma unroll
    for (int i = 0; i < 4; i++) {
        aP[i] = zf8 + (size_t)(rowBase + wr * 64 + i * 16 + l15) * D_DIM + q * 16;
        bP[i] = zf8 + (size_t)(colBase + wc * 64 + i * 16 + l15) * D_DIM + q * 16;
    }

    f32x4_t acc[4][4] = {};

    i64x2 aCur[4], bCur[4];
    #pragma unroll
    for (int i = 0; i < 4; i++) {
        aCur[i] = *(const i64x2*)(aP[i]);
        bCur[i] = *(const i64x2*)(bP[i]);
    }

    #pragma unroll
    for (int b = 0; b < NKB; b++) {
        i64x2 aNxt[4], bNxt[4];
        if (b + 1 < NKB) {
            const int off = (b + 1) * 64;
            #pragma unroll
            for (int i = 0; i < 4; i++) {
                aNxt[i] = *(const i64x2*)(aP[i] + off);
                bNxt[i] = *(const i64x2*)(bP[i] + off);
            }
        }
        #pragma unroll
        for (int i = 0; i < 4; i++)
            #pragma unroll
            for (int j = 0; j < 4; j++) {
                acc[i][j] = __builtin_amdgcn_mfma_f32_16x16x32_fp8_fp8(
                    aCur[i][0], bCur[j][0], acc[i][j], 0, 0, 0);
                acc[i][j] = __builtin_amdgcn_mfma_f32_16x16x32_fp8_fp8(
                    aCur[i][1], bCur[j][1], acc[i][j], 0, 0, 0);
            }
        if (b + 1 < NKB) {
            #pragma unroll
            for (int i = 0; i < 4; i++) { aCur[i] = aNxt[i]; bCur[i] = bNxt[i]; }
        }
    }

    // Epilogue. C/D layout (16x16 family): col = lane&15, row = (lane>>4)*4 + reg.
    float colacc[4] = {0.f, 0.f, 0.f, 0.f};
    #pragma unroll
    for (int i = 0; i < 4; i++) {
        #pragma unroll
        for (int r = 0; r < 4; r++) {
            const int row = rowBase + wr * 64 + i * 16 + q * 4 + r;
            float rs = 0.0f;
            #pragma unroll
            for (int j = 0; j < 4; j++) {
                const int col = colBase + wc * 64 + j * 16 + l15;
                const float c = acc[i][j][r];
                float e = __expf(c);
                if (isDiag && col == row) e = 0.0f;
                rs += e;
                colacc[j] += e;
                if (hasPos && col == row + HALF_N) { pos[row] = c; pos[col] = c; }
            }
            rs += __shfl_xor(rs, 1); rs += __shfl_xor(rs, 2);
            rs += __shfl_xor(rs, 4); rs += __shfl_xor(rs, 8);
            if (l15 == 0) atomicAdd(&rowsum[row], rs);
        }
    }
    if (!isDiag) {
        #pragma unroll
        for (int j = 0; j < 4; j++) {
            float cs = colacc[j];
            cs += __shfl_xor(cs, 16);
            cs += __shfl_xor(cs, 32);
            if (q == 0) atomicAdd(&rowsum[colBase + wc * 64 + j * 16 + l15], cs);
        }
    }
}

// Kernel 3: mean over rows of (log(rowsum) - pos) -> scalar (out pre-zeroed).
__global__ __launch_bounds__(256) void k_finalize(
    const float* __restrict__ rowsum, const float* __restrict__ pos,
    float* __restrict__ out)
{
    const int t = threadIdx.x;
    const int i = blockIdx.x * 256 + t;
    float s = logf(rowsum[i]) - pos[i];
    #pragma unroll
    for (int m = 1; m < 64; m <<= 1) s += __shfl_xor(s, m, 64);
    __shared__ float red[4];
    if ((t & 63) == 0) red[t >> 6] = s;
    __syncthreads();
    if (t == 0)
        atomicAdd(out, (red[0] + red[1] + red[2] + red[3]) * (1.0f / (float)N_TOT));
}

extern "C" void kernel_launch(void* const* d_in, const int* in_sizes, int n_in,
                              void* d_out, int out_size, void* d_ws, size_t ws_size,
                              hipStream_t stream) {
    const float* p1 = (const float*)d_in[0];
    const float* p2 = (const float*)d_in[1];

    unsigned char* zf8 = (unsigned char*)d_ws;                          // 4 MB
    float* rowsum = (float*)((char*)d_ws + (size_t)N_TOT * D_DIM);      // 32 KB
    float* pos    = rowsum + N_TOT;                                     // 32 KB
    float* outp   = (float*)d_out;

    k_normalize<<<N_TOT / 4, 256, 0, stream>>>(p1, p2, zf8, rowsum, outp);
    k_gemm<<<NTILES, 256, 0, stream>>>(zf8, rowsum, pos);
    k_finalize<<<N_TOT / 256, 256, 0, stream>>>(rowsum, pos, outp);
}

// Round 10
// 127.202 us; speedup vs baseline: 1.2191x; 1.2191x over previous
//
#include <hip/hip_runtime.h>
#include <hip/hip_bf16.h>
#include <math.h>

#define N_TOT 8192
#define HALF_N 4096
#define D_DIM 512
#define BM 128
#define BK 64          // fp8 bytes per K-chunk; 8 K-iterations, 64B LDS rows
#define NKIT (D_DIM / BK)
#define NTILES 2080    // 64*65/2 upper-triangle 128x128 tiles

typedef float f32x16_t __attribute__((ext_vector_type(16)));

typedef __attribute__((address_space(1))) unsigned int g_u32;
typedef __attribute__((address_space(3))) unsigned int l_u32;

// Kernel 1: L2-normalize rows of [p1;p2] -> fp8 e4m3 Z (plain row-major);
// zero rowsum + out.
__global__ __launch_bounds__(256) void k_normalize(
    const float* __restrict__ p1, const float* __restrict__ p2,
    unsigned char* __restrict__ zf8, float* __restrict__ rowsum,
    float* __restrict__ out)
{
    const int w = threadIdx.x >> 6;
    const int lane = threadIdx.x & 63;
    const int row = blockIdx.x * 4 + w;

    if (threadIdx.x < 4) rowsum[blockIdx.x * 4 + threadIdx.x] = 0.0f;
    if (blockIdx.x == 0 && threadIdx.x == 0) out[0] = 0.0f;

    const float* src = (row < HALF_N) ? p1 + (size_t)row * D_DIM
                                      : p2 + (size_t)(row - HALF_N) * D_DIM;
    float4 a = *(const float4*)(src + lane * 4);
    float4 b = *(const float4*)(src + 256 + lane * 4);
    float s = a.x*a.x + a.y*a.y + a.z*a.z + a.w*a.w
            + b.x*b.x + b.y*b.y + b.z*b.z + b.w*b.w;
    #pragma unroll
    for (int m = 1; m < 64; m <<= 1) s += __shfl_xor(s, m, 64);
    float inv = 1.0f / fmaxf(sqrtf(s), 1e-8f);

    int pk0 = __builtin_amdgcn_cvt_pk_fp8_f32(a.x * inv, a.y * inv, 0, false);
    pk0     = __builtin_amdgcn_cvt_pk_fp8_f32(a.z * inv, a.w * inv, pk0, true);
    int pk1 = __builtin_amdgcn_cvt_pk_fp8_f32(b.x * inv, b.y * inv, 0, false);
    pk1     = __builtin_amdgcn_cvt_pk_fp8_f32(b.z * inv, b.w * inv, pk1, true);

    unsigned char* dst = zf8 + (size_t)row * D_DIM;
    *(int*)(dst + lane * 4) = pk0;
    *(int*)(dst + 256 + lane * 4) = pk1;
}

// Kernel 2: upper-triangle tiles of sim = Z*Z^T via fp8 MFMA **32x32x16**
// (2x FLOP per LDS byte vs 16x16x32: halves fragment LDS traffic, which
// R8's counters showed co-binding with MFMA). Double-buffered LDS, R8's
// proven staging + XOR chunk swizzle. No __threadfence (R5/R6 lesson).
__global__ __launch_bounds__(256, 3) void k_gemm(
    const unsigned char* __restrict__ zf8,
    float* __restrict__ rowsum, float* __restrict__ pos)
{
    __shared__ __align__(16) unsigned char As[2][BM * BK];  // 2 x 8 KB
    __shared__ __align__(16) unsigned char Bs[2][BM * BK];  // 2 x 8 KB

    const int tid = threadIdx.x;
    const int lane = tid & 63;
    const int w = tid >> 6;
    const int wr = w >> 1, wc = w & 1;
    const int l31 = lane & 31, h = lane >> 5;

    // triangular block mapping: t -> (bx >= by)
    const int t = blockIdx.x;
    int bi = (int)((sqrtf(8.0f * (float)t + 1.0f) - 1.0f) * 0.5f);
    while ((bi + 1) * (bi + 2) / 2 <= t) ++bi;
    while (bi * (bi + 1) / 2 > t) --bi;
    const int bx = bi;                       // col tile (larger)
    const int by = t - bi * (bi + 1) / 2;    // row tile
    const bool isDiag = (bx == by);
    const bool hasPos = (bx - by == 32);
    const int rowBase = by * BM;
    const int colBase = bx * BM;

    // staging (R8-proven): 16B chunks, dest chunk = tid / 256+tid, source
    // chunk XOR-swizzled: LDS slot cc of row r holds source chunk cc^((r>>1)&3)
    const int ci0 = tid;
    const int ci1 = 256 + tid;
    const int r0 = ci0 >> 2, cc0 = ci0 & 3;
    const int r1 = ci1 >> 2, cc1 = ci1 & 3;
    const int gc0 = cc0 ^ ((r0 >> 1) & 3);
    const int gc1 = cc1 ^ ((r1 >> 1) & 3);

    const unsigned char* gA0 = zf8 + (size_t)(rowBase + r0) * D_DIM + gc0 * 16;
    const unsigned char* gA1 = zf8 + (size_t)(rowBase + r1) * D_DIM + gc1 * 16;
    const unsigned char* gB0 = zf8 + (size_t)(colBase + r0) * D_DIM + gc0 * 16;
    const unsigned char* gB1 = zf8 + (size_t)(colBase + r1) * D_DIM + gc1 * 16;

    f32x16_t acc[2][2] = {};

    __builtin_amdgcn_global_load_lds((const g_u32*)gA0, (l_u32*)&As[0][ci0 * 16], 16, 0, 0);
    __builtin_amdgcn_global_load_lds((const g_u32*)gA1, (l_u32*)&As[0][ci1 * 16], 16, 0, 0);
    __builtin_amdgcn_global_load_lds((const g_u32*)gB0, (l_u32*)&Bs[0][ci0 * 16], 16, 0, 0);
    __builtin_amdgcn_global_load_lds((const g_u32*)gB1, (l_u32*)&Bs[0][ci1 * 16], 16, 0, 0);

    // fragment rows for this wave (32x32 blocks): A rows wr*64+i*32+l31,
    // B cols wc*64+j*32+l31; k-piece for h at byte h*8 of chunk kk.
    const int ra0 = wr * 64 + 0 * 32 + l31;
    const int ra1 = wr * 64 + 1 * 32 + l31;
    const int rb0 = wc * 64 + 0 * 32 + l31;
    const int rb1 = wc * 64 + 1 * 32 + l31;
    const int sa0 = (ra0 >> 1) & 3, sa1 = (ra1 >> 1) & 3;
    const int sb0 = (rb0 >> 1) & 3, sb1 = (rb1 >> 1) & 3;

    #pragma unroll
    for (int it = 0; it < NKIT; it++) {
        const int cur = it & 1;
        __syncthreads();  // drains vmcnt -> buf[cur] ready; buf[1-cur] free

        if (it + 1 < NKIT) {
            const int kb = (it + 1) * BK;
            const int nxt = 1 - cur;
            __builtin_amdgcn_global_load_lds((const g_u32*)(gA0 + kb), (l_u32*)&As[nxt][ci0 * 16], 16, 0, 0);
            __builtin_amdgcn_global_load_lds((const g_u32*)(gA1 + kb), (l_u32*)&As[nxt][ci1 * 16], 16, 0, 0);
            __builtin_amdgcn_global_load_lds((const g_u32*)(gB0 + kb), (l_u32*)&Bs[nxt][ci0 * 16], 16, 0, 0);
            __builtin_amdgcn_global_load_lds((const g_u32*)(gB1 + kb), (l_u32*)&Bs[nxt][ci1 * 16], 16, 0, 0);
        }

        #pragma unroll
        for (int kk = 0; kk < 4; kk++) {   // 4 k-steps of 16 per BK=64
            const long long a0 = *(const long long*)&As[cur][ra0 * BK + (kk ^ sa0) * 16 + h * 8];
            const long long a1 = *(const long long*)&As[cur][ra1 * BK + (kk ^ sa1) * 16 + h * 8];
            const long long b0 = *(const long long*)&Bs[cur][rb0 * BK + (kk ^ sb0) * 16 + h * 8];
            const long long b1 = *(const long long*)&Bs[cur][rb1 * BK + (kk ^ sb1) * 16 + h * 8];
            acc[0][0] = __builtin_amdgcn_mfma_f32_32x32x16_fp8_fp8(a0, b0, acc[0][0], 0, 0, 0);
            acc[0][1] = __builtin_amdgcn_mfma_f32_32x32x16_fp8_fp8(a0, b1, acc[0][1], 0, 0, 0);
            acc[1][0] = __builtin_amdgcn_mfma_f32_32x32x16_fp8_fp8(a1, b0, acc[1][0], 0, 0, 0);
            acc[1][1] = __builtin_amdgcn_mfma_f32_32x32x16_fp8_fp8(a1, b1, acc[1][1], 0, 0, 0);
        }
    }

    // Epilogue. 32x32 C/D layout (measured, dtype-independent):
    // col = lane&31, row = (reg&3) + 8*(reg>>2) + 4*(lane>>5).
    float colacc[2][1]; colacc[0][0] = 0.f; colacc[1][0] = 0.f;
    float ca0 = 0.f, ca1 = 0.f;
    #pragma unroll
    for (int i = 0; i < 2; i++) {
        #pragma unroll
        for (int reg = 0; reg < 16; reg++) {
            const int row = rowBase + wr * 64 + i * 32 + (reg & 3) + 8 * (reg >> 2) + 4 * h;
            float rs = 0.0f;
            #pragma unroll
            for (int j = 0; j < 2; j++) {
                const int col = colBase + wc * 64 + j * 32 + l31;
                const float c = acc[i][j][reg];
                float e = __expf(c);
                if (isDiag && col == row) e = 0.0f;
                rs += e;
                if (j == 0) ca0 += e; else ca1 += e;
                if (hasPos && col == row + HALF_N) { pos[row] = c; pos[col] = c; }
            }
            rs += __shfl_xor(rs, 1);  rs += __shfl_xor(rs, 2);
            rs += __shfl_xor(rs, 4);  rs += __shfl_xor(rs, 8);
            rs += __shfl_xor(rs, 16);
            if (l31 == 0) atomicAdd(&rowsum[row], rs);
        }
    }
    if (!isDiag) {
        ca0 += __shfl_xor(ca0, 32);   // combine h halves (rows split by h)
        ca1 += __shfl_xor(ca1, 32);
        if (h == 0) {
            atomicAdd(&rowsum[colBase + wc * 64 + 0 * 32 + l31], ca0);
            atomicAdd(&rowsum[colBase + wc * 64 + 1 * 32 + l31], ca1);
        }
    }
}

// Kernel 3: mean over rows of (log(rowsum) - pos) -> scalar (out pre-zeroed).
__global__ __launch_bounds__(256) void k_finalize(
    const float* __restrict__ rowsum, const float* __restrict__ pos,
    float* __restrict__ out)
{
    const int t = threadIdx.x;
    const int i = blockIdx.x * 256 + t;
    float s = logf(rowsum[i]) - pos[i];
    #pragma unroll
    for (int m = 1; m < 64; m <<= 1) s += __shfl_xor(s, m, 64);
    __shared__ float red[4];
    if ((t & 63) == 0) red[t >> 6] = s;
    __syncthreads();
    if (t == 0)
        atomicAdd(out, (red[0] + red[1] + red[2] + red[3]) * (1.0f / (float)N_TOT));
}

extern "C" void kernel_launch(void* const* d_in, const int* in_sizes, int n_in,
                              void* d_out, int out_size, void* d_ws, size_t ws_size,
                              hipStream_t stream) {
    const float* p1 = (const float*)d_in[0];
    const float* p2 = (const float*)d_in[1];

    unsigned char* zf8 = (unsigned char*)d_ws;                          // 4 MB
    float* rowsum = (float*)((char*)d_ws + (size_t)N_TOT * D_DIM);      // 32 KB
    float* pos    = rowsum + N_TOT;                                     // 32 KB
    float* outp   = (float*)d_out;

    k_normalize<<<N_TOT / 4, 256, 0, stream>>>(p1, p2, zf8, rowsum, outp);
    k_gemm<<<NTILES, 256, 0, stream>>>(zf8, rowsum, pos);
    k_finalize<<<N_TOT / 256, 256, 0, stream>>>(rowsum, pos, outp);
}

// Round 11
// 106.686 us; speedup vs baseline: 1.4535x; 1.1923x over previous
//
#include <hip/hip_runtime.h>
#include <hip/hip_bf16.h>
#include <math.h>

#define N_TOT 8192
#define HALF_N 4096
#define D_DIM 512
#define BM 128
#define BK 64          // fp8 bytes per K-chunk; 8 K-iterations, 64B LDS rows
#define NKIT (D_DIM / BK)
#define NTILES 2080    // 64*65/2 upper-triangle 128x128 tiles

typedef float f32x4_t __attribute__((ext_vector_type(4)));
typedef long long i64x2 __attribute__((ext_vector_type(2)));

typedef __attribute__((address_space(1))) unsigned int g_u32;
typedef __attribute__((address_space(3))) unsigned int l_u32;

// Kernel 1: L2-normalize rows of [p1;p2] -> fp8 e4m3 Z in k-PERMUTED layout
// (validated R9): within each 64B k-block, source byte k (q=(k>>3)&3,
// h=(k>>5)&1, r=k&7) stored at q*16 + h*8 + r. Both GEMM operands use the
// same bijection, so dot products are unaffected; a lane's two 8B MFMA
// k-pieces become one contiguous 16B chunk.
__global__ __launch_bounds__(256) void k_normalize(
    const float* __restrict__ p1, const float* __restrict__ p2,
    unsigned char* __restrict__ zf8, float* __restrict__ rowsum,
    float* __restrict__ out)
{
    const int w = threadIdx.x >> 6;
    const int lane = threadIdx.x & 63;
    const int row = blockIdx.x * 4 + w;

    if (threadIdx.x < 4) rowsum[blockIdx.x * 4 + threadIdx.x] = 0.0f;
    if (blockIdx.x == 0 && threadIdx.x == 0) out[0] = 0.0f;

    const float* src = (row < HALF_N) ? p1 + (size_t)row * D_DIM
                                      : p2 + (size_t)(row - HALF_N) * D_DIM;
    float4 a = *(const float4*)(src + lane * 4);
    float4 b = *(const float4*)(src + 256 + lane * 4);
    float s = a.x*a.x + a.y*a.y + a.z*a.z + a.w*a.w
            + b.x*b.x + b.y*b.y + b.z*b.z + b.w*b.w;
    #pragma unroll
    for (int m = 1; m < 64; m <<= 1) s += __shfl_xor(s, m, 64);
    float inv = 1.0f / fmaxf(sqrtf(s), 1e-8f);

    int pk0 = __builtin_amdgcn_cvt_pk_fp8_f32(a.x * inv, a.y * inv, 0, false);
    pk0     = __builtin_amdgcn_cvt_pk_fp8_f32(a.z * inv, a.w * inv, pk0, true);
    int pk1 = __builtin_amdgcn_cvt_pk_fp8_f32(b.x * inv, b.y * inv, 0, false);
    pk1     = __builtin_amdgcn_cvt_pk_fp8_f32(b.z * inv, b.w * inv, pk1, true);

    unsigned char* dst = zf8 + (size_t)row * D_DIM;
    const int o0 = lane * 4;
    const int o1 = 256 + lane * 4;
    const int d0 = (o0 & ~63) + ((o0 >> 3) & 3) * 16 + ((o0 >> 5) & 1) * 8 + (o0 & 4);
    const int d1 = (o1 & ~63) + ((o1 >> 3) & 3) * 16 + ((o1 >> 5) & 1) * 8 + (o1 & 4);
    *(int*)(dst + d0) = pk0;
    *(int*)(dst + d1) = pk1;
}

// Kernel 2: upper-triangle tiles of sim = Z*Z^T via fp8 MFMA 16x16x32.
// R8's double-buffered LDS loop + k-permuted layout: each fragment is ONE
// ds_read_b128 (R2-measured 0 conflicts) instead of two b64 (4.26M conflict
// cycles in R8). XOR chunk swizzle spreads rows over banks. 60 VGPR + 64
// AGPR = 124 <= 128 -> 4 waves/EU requested. No __threadfence (R5/R6).
__global__ __launch_bounds__(256, 4) void k_gemm(
    const unsigned char* __restrict__ zf8,
    float* __restrict__ rowsum, float* __restrict__ pos)
{
    __shared__ __align__(16) unsigned char As[2][BM * BK];  // 2 x 8 KB
    __shared__ __align__(16) unsigned char Bs[2][BM * BK];  // 2 x 8 KB

    const int tid = threadIdx.x;
    const int lane = tid & 63;
    const int w = tid >> 6;
    const int wr = w >> 1, wc = w & 1;
    const int q = lane >> 4, l15 = lane & 15;

    // triangular block mapping: t -> (bx >= by)
    const int t = blockIdx.x;
    int bi = (int)((sqrtf(8.0f * (float)t + 1.0f) - 1.0f) * 0.5f);
    while ((bi + 1) * (bi + 2) / 2 <= t) ++bi;
    while (bi * (bi + 1) / 2 > t) --bi;
    const int bx = bi;                       // col tile (larger)
    const int by = t - bi * (bi + 1) / 2;    // row tile
    const bool isDiag = (bx == by);
    const bool hasPos = (bx - by == 32);
    const int rowBase = by * BM;
    const int colBase = bx * BM;

    // staging (R8-proven): 16B chunks, dest chunk = tid / 256+tid,
    // LDS slot cc of row r holds source chunk cc ^ ((r>>1)&3).
    const int ci0 = tid;
    const int ci1 = 256 + tid;
    const int r0 = ci0 >> 2, cc0 = ci0 & 3;
    const int r1 = ci1 >> 2, cc1 = ci1 & 3;
    const int gc0 = cc0 ^ ((r0 >> 1) & 3);
    const int gc1 = cc1 ^ ((r1 >> 1) & 3);

    const unsigned char* gA0 = zf8 + (size_t)(rowBase + r0) * D_DIM + gc0 * 16;
    const unsigned char* gA1 = zf8 + (size_t)(rowBase + r1) * D_DIM + gc1 * 16;
    const unsigned char* gB0 = zf8 + (size_t)(colBase + r0) * D_DIM + gc0 * 16;
    const unsigned char* gB1 = zf8 + (size_t)(colBase + r1) * D_DIM + gc1 * 16;

    f32x4_t acc[4][4] = {};

    __builtin_amdgcn_global_load_lds((const g_u32*)gA0, (l_u32*)&As[0][ci0 * 16], 16, 0, 0);
    __builtin_amdgcn_global_load_lds((const g_u32*)gA1, (l_u32*)&As[0][ci1 * 16], 16, 0, 0);
    __builtin_amdgcn_global_load_lds((const g_u32*)gB0, (l_u32*)&Bs[0][ci0 * 16], 16, 0, 0);
    __builtin_amdgcn_global_load_lds((const g_u32*)gB1, (l_u32*)&Bs[0][ci1 * 16], 16, 0, 0);

    // fragment addresses: lane (q,l15), row ra -> source chunk q at LDS slot
    // q ^ ((ra>>1)&3); 16B = [h=0 piece | h=1 piece] (k-permuted layout).
    #pragma unroll
    for (int it = 0; it < NKIT; it++) {
        const int cur = it & 1;
        __syncthreads();  // drains vmcnt -> buf[cur] ready; buf[1-cur] free

        if (it + 1 < NKIT) {
            const int kb = (it + 1) * BK;
            const int nxt = 1 - cur;
            __builtin_amdgcn_global_load_lds((const g_u32*)(gA0 + kb), (l_u32*)&As[nxt][ci0 * 16], 16, 0, 0);
            __builtin_amdgcn_global_load_lds((const g_u32*)(gA1 + kb), (l_u32*)&As[nxt][ci1 * 16], 16, 0, 0);
            __builtin_amdgcn_global_load_lds((const g_u32*)(gB0 + kb), (l_u32*)&Bs[nxt][ci0 * 16], 16, 0, 0);
            __builtin_amdgcn_global_load_lds((const g_u32*)(gB1 + kb), (l_u32*)&Bs[nxt][ci1 * 16], 16, 0, 0);
        }

        i64x2 aF[4], bF[4];
        #pragma unroll
        for (int i = 0; i < 4; i++) {
            const int ra = wr * 64 + i * 16 + l15;
            const int rb = wc * 64 + i * 16 + l15;
            aF[i] = *(const i64x2*)&As[cur][ra * BK + (q ^ ((ra >> 1) & 3)) * 16];
            bF[i] = *(const i64x2*)&Bs[cur][rb * BK + (q ^ ((rb >> 1) & 3)) * 16];
        }
        #pragma unroll
        for (int h = 0; h < 2; h++)
            #pragma unroll
            for (int i = 0; i < 4; i++)
                #pragma unroll
                for (int j = 0; j < 4; j++)
                    acc[i][j] = __builtin_amdgcn_mfma_f32_16x16x32_fp8_fp8(
                        aF[i][h], bF[j][h], acc[i][j], 0, 0, 0);
    }

    // Epilogue. C/D layout (16x16 family): col = lane&15, row = (lane>>4)*4 + reg.
    float colacc[4] = {0.f, 0.f, 0.f, 0.f};
    #pragma unroll
    for (int i = 0; i < 4; i++) {
        #pragma unroll
        for (int r = 0; r < 4; r++) {
            const int row = rowBase + wr * 64 + i * 16 + q * 4 + r;
            float rs = 0.0f;
            #pragma unroll
            for (int j = 0; j < 4; j++) {
                const int col = colBase + wc * 64 + j * 16 + l15;
                const float c = acc[i][j][r];
                float e = __expf(c);
                if (isDiag && col == row) e = 0.0f;
                rs += e;
                colacc[j] += e;
                if (hasPos && col == row + HALF_N) { pos[row] = c; pos[col] = c; }
            }
            rs += __shfl_xor(rs, 1); rs += __shfl_xor(rs, 2);
            rs += __shfl_xor(rs, 4); rs += __shfl_xor(rs, 8);
            if (l15 == 0) atomicAdd(&rowsum[row], rs);
        }
    }
    if (!isDiag) {
        #pragma unroll
        for (int j = 0; j < 4; j++) {
            float cs = colacc[j];
            cs += __shfl_xor(cs, 16);
            cs += __shfl_xor(cs, 32);
            if (q == 0) atomicAdd(&rowsum[colBase + wc * 64 + j * 16 + l15], cs);
        }
    }
}

// Kernel 3: mean over rows of (log(rowsum) - pos) -> scalar (out pre-zeroed).
__global__ __launch_bounds__(256) void k_finalize(
    const float* __restrict__ rowsum, const float* __restrict__ pos,
    float* __restrict__ out)
{
    const int t = threadIdx.x;
    const int i = blockIdx.x * 256 + t;
    float s = logf(rowsum[i]) - pos[i];
    #pragma unroll
    for (int m = 1; m < 64; m <<= 1) s += __shfl_xor(s, m, 64);
    __shared__ float red[4];
    if ((t & 63) == 0) red[t >> 6] = s;
    __syncthreads();
    if (t == 0)
        atomicAdd(out, (red[0] + red[1] + red[2] + red[3]) * (1.0f / (float)N_TOT));
}

extern "C" void kernel_launch(void* const* d_in, const int* in_sizes, int n_in,
                              void* d_out, int out_size, void* d_ws, size_t ws_size,
                              hipStream_t stream) {
    const float* p1 = (const float*)d_in[0];
    const float* p2 = (const float*)d_in[1];

    unsigned char* zf8 = (unsigned char*)d_ws;                          // 4 MB
    float* rowsum = (float*)((char*)d_ws + (size_t)N_TOT * D_DIM);      // 32 KB
    float* pos    = rowsum + N_TOT;                                     // 32 KB
    float* outp   = (float*)d_out;

    k_normalize<<<N_TOT / 4, 256, 0, stream>>>(p1, p2, zf8, rowsum, outp);
    k_gemm<<<NTILES, 256, 0, stream>>>(zf8, rowsum, pos);
    k_finalize<<<N_TOT / 256, 256, 0, stream>>>(rowsum, pos, outp);
}

// Round 12
// 105.384 us; speedup vs baseline: 1.4715x; 1.0124x over previous
//
#include <hip/hip_runtime.h>
#include <hip/hip_bf16.h>
#include <math.h>

#define N_TOT 8192
#define HALF_N 4096
#define D_DIM 512
#define BM 128
#define BK 64          // fp8 bytes per K-chunk; 8 K-iterations, 64B LDS rows
#define NKIT (D_DIM / BK)
#define NTILES 2080    // 64*65/2 upper-triangle 128x128 tiles

// s_waitcnt imm: vmcnt[3:0] | expcnt<<4 | lgkmcnt<<8 (expcnt/lgkmcnt = max -> unconstrained)
#define WAIT_VM4 0xF74
#define WAIT_VM0 0xF70

typedef float f32x4_t __attribute__((ext_vector_type(4)));
typedef long long i64x2 __attribute__((ext_vector_type(2)));

typedef __attribute__((address_space(1))) unsigned int g_u32;
typedef __attribute__((address_space(3))) unsigned int l_u32;

// Kernel 1: L2-normalize rows of [p1;p2] -> fp8 e4m3 Z in k-PERMUTED layout
// (validated R9/R11): within each 64B k-block, source byte k (q=(k>>3)&3,
// h=(k>>5)&1) stored at q*16 + h*8 + (k&7). Both GEMM operands use the same
// bijection, so dot products are unaffected; a lane's two 8B MFMA k-pieces
// are one contiguous 16B chunk -> single ds_read_b128, zero bank conflicts.
__global__ __launch_bounds__(256) void k_normalize(
    const float* __restrict__ p1, const float* __restrict__ p2,
    unsigned char* __restrict__ zf8, float* __restrict__ rowsum,
    float* __restrict__ out)
{
    const int w = threadIdx.x >> 6;
    const int lane = threadIdx.x & 63;
    const int row = blockIdx.x * 4 + w;

    if (threadIdx.x < 4) rowsum[blockIdx.x * 4 + threadIdx.x] = 0.0f;
    if (blockIdx.x == 0 && threadIdx.x == 0) out[0] = 0.0f;

    const float* src = (row < HALF_N) ? p1 + (size_t)row * D_DIM
                                      : p2 + (size_t)(row - HALF_N) * D_DIM;
    float4 a = *(const float4*)(src + lane * 4);
    float4 b = *(const float4*)(src + 256 + lane * 4);
    float s = a.x*a.x + a.y*a.y + a.z*a.z + a.w*a.w
            + b.x*b.x + b.y*b.y + b.z*b.z + b.w*b.w;
    #pragma unroll
    for (int m = 1; m < 64; m <<= 1) s += __shfl_xor(s, m, 64);
    float inv = 1.0f / fmaxf(sqrtf(s), 1e-8f);

    int pk0 = __builtin_amdgcn_cvt_pk_fp8_f32(a.x * inv, a.y * inv, 0, false);
    pk0     = __builtin_amdgcn_cvt_pk_fp8_f32(a.z * inv, a.w * inv, pk0, true);
    int pk1 = __builtin_amdgcn_cvt_pk_fp8_f32(b.x * inv, b.y * inv, 0, false);
    pk1     = __builtin_amdgcn_cvt_pk_fp8_f32(b.z * inv, b.w * inv, pk1, true);

    unsigned char* dst = zf8 + (size_t)row * D_DIM;
    const int o0 = lane * 4;
    const int o1 = 256 + lane * 4;
    const int d0 = (o0 & ~63) + ((o0 >> 3) & 3) * 16 + ((o0 >> 5) & 1) * 8 + (o0 & 4);
    const int d1 = (o1 & ~63) + ((o1 >> 3) & 3) * 16 + ((o1 >> 5) & 1) * 8 + (o1 & 4);
    *(int*)(dst + d0) = pk0;
    *(int*)(dst + d1) = pk1;
}

// Kernel 2: upper-triangle tiles of sim = Z*Z^T via fp8 MFMA 16x16x32.
// TRIPLE-buffered LDS, prefetch distance 2, manual `s_waitcnt vmcnt(4)` +
// raw s_barrier: each barrier keeps the NEXT iteration's 4 loads in flight
// (waits only the 4 oldest = current buffer), the AITER "never vmcnt(0)"
// pattern that __syncthreads cannot express. WAW safe: prefetch for
// buf[(it+2)%3] is issued after the barrier ending all reads of it.
// No __threadfence (R5/R6 lesson). k-permuted layout (R11): 0 conflicts.
__global__ __launch_bounds__(256, 4) void k_gemm(
    const unsigned char* __restrict__ zf8,
    float* __restrict__ rowsum, float* __restrict__ pos)
{
    __shared__ __align__(16) unsigned char As[3][BM * BK];  // 3 x 8 KB
    __shared__ __align__(16) unsigned char Bs[3][BM * BK];  // 3 x 8 KB

    const int tid = threadIdx.x;
    const int lane = tid & 63;
    const int w = tid >> 6;
    const int wr = w >> 1, wc = w & 1;
    const int q = lane >> 4, l15 = lane & 15;

    // triangular block mapping: t -> (bx >= by)
    const int t = blockIdx.x;
    int bi = (int)((sqrtf(8.0f * (float)t + 1.0f) - 1.0f) * 0.5f);
    while ((bi + 1) * (bi + 2) / 2 <= t) ++bi;
    while (bi * (bi + 1) / 2 > t) --bi;
    const int bx = bi;                       // col tile (larger)
    const int by = t - bi * (bi + 1) / 2;    // row tile
    const bool isDiag = (bx == by);
    const bool hasPos = (bx - by == 32);
    const int rowBase = by * BM;
    const int colBase = bx * BM;

    // staging (R8/R11-proven): 16B chunks, dest chunk = tid / 256+tid,
    // LDS slot cc of row r holds source chunk cc ^ ((r>>1)&3).
    const int ci0 = tid;
    const int ci1 = 256 + tid;
    const int r0 = ci0 >> 2, cc0 = ci0 & 3;
    const int r1 = ci1 >> 2, cc1 = ci1 & 3;
    const int gc0 = cc0 ^ ((r0 >> 1) & 3);
    const int gc1 = cc1 ^ ((r1 >> 1) & 3);

    const unsigned char* gA0 = zf8 + (size_t)(rowBase + r0) * D_DIM + gc0 * 16;
    const unsigned char* gA1 = zf8 + (size_t)(rowBase + r1) * D_DIM + gc1 * 16;
    const unsigned char* gB0 = zf8 + (size_t)(colBase + r0) * D_DIM + gc0 * 16;
    const unsigned char* gB1 = zf8 + (size_t)(colBase + r1) * D_DIM + gc1 * 16;

    auto stage = [&](int buf, int kblk) {
        const int kb = kblk * BK;
        __builtin_amdgcn_global_load_lds((const g_u32*)(gA0 + kb), (l_u32*)&As[buf][ci0 * 16], 16, 0, 0);
        __builtin_amdgcn_global_load_lds((const g_u32*)(gA1 + kb), (l_u32*)&As[buf][ci1 * 16], 16, 0, 0);
        __builtin_amdgcn_global_load_lds((const g_u32*)(gB0 + kb), (l_u32*)&Bs[buf][ci0 * 16], 16, 0, 0);
        __builtin_amdgcn_global_load_lds((const g_u32*)(gB1 + kb), (l_u32*)&Bs[buf][ci1 * 16], 16, 0, 0);
    };

    f32x4_t acc[4][4] = {};

    stage(0, 0);   // 4 vm ops (oldest)
    stage(1, 1);   // 4 vm ops

    #pragma unroll
    for (int it = 0; it < NKIT; it++) {
        const int cur = it % 3;
        // wait ONLY the 4 oldest loads (= buf[cur]); keep next iter's 4 in flight
        if (it + 1 < NKIT) __builtin_amdgcn_s_waitcnt(WAIT_VM4);
        else               __builtin_amdgcn_s_waitcnt(WAIT_VM0);
        __builtin_amdgcn_s_barrier();

        if (it + 2 < NKIT) stage((it + 2) % 3, it + 2);

        i64x2 aF[4], bF[4];
        #pragma unroll
        for (int i = 0; i < 4; i++) {
            const int ra = wr * 64 + i * 16 + l15;
            const int rb = wc * 64 + i * 16 + l15;
            aF[i] = *(const i64x2*)&As[cur][ra * BK + (q ^ ((ra >> 1) & 3)) * 16];
            bF[i] = *(const i64x2*)&Bs[cur][rb * BK + (q ^ ((rb >> 1) & 3)) * 16];
        }
        #pragma unroll
        for (int h = 0; h < 2; h++)
            #pragma unroll
            for (int i = 0; i < 4; i++)
                #pragma unroll
                for (int j = 0; j < 4; j++)
                    acc[i][j] = __builtin_amdgcn_mfma_f32_16x16x32_fp8_fp8(
                        aF[i][h], bF[j][h], acc[i][j], 0, 0, 0);
    }

    // Epilogue. C/D layout (16x16 family): col = lane&15, row = (lane>>4)*4 + reg.
    float colacc[4] = {0.f, 0.f, 0.f, 0.f};
    #pragma unroll
    for (int i = 0; i < 4; i++) {
        #pragma unroll
        for (int r = 0; r < 4; r++) {
            const int row = rowBase + wr * 64 + i * 16 + q * 4 + r;
            float rs = 0.0f;
            #pragma unroll
            for (int j = 0; j < 4; j++) {
                const int col = colBase + wc * 64 + j * 16 + l15;
                const float c = acc[i][j][r];
                float e = __expf(c);
                if (isDiag && col == row) e = 0.0f;
                rs += e;
                colacc[j] += e;
                if (hasPos && col == row + HALF_N) { pos[row] = c; pos[col] = c; }
            }
            rs += __shfl_xor(rs, 1); rs += __shfl_xor(rs, 2);
            rs += __shfl_xor(rs, 4); rs += __shfl_xor(rs, 8);
            if (l15 == 0) atomicAdd(&rowsum[row], rs);
        }
    }
    if (!isDiag) {
        #pragma unroll
        for (int j = 0; j < 4; j++) {
            float cs = colacc[j];
            cs += __shfl_xor(cs, 16);
            cs += __shfl_xor(cs, 32);
            if (q == 0) atomicAdd(&rowsum[colBase + wc * 64 + j * 16 + l15], cs);
        }
    }
}

// Kernel 3: mean over rows of (log(rowsum) - pos) -> scalar (out pre-zeroed).
__global__ __launch_bounds__(256) void k_finalize(
    const float* __restrict__ rowsum, const float* __restrict__ pos,
    float* __restrict__ out)
{
    const int t = threadIdx.x;
    const int i = blockIdx.x * 256 + t;
    float s = logf(rowsum[i]) - pos[i];
    #pragma unroll
    for (int m = 1; m < 64; m <<= 1) s += __shfl_xor(s, m, 64);
    __shared__ float red[4];
    if ((t & 63) == 0) red[t >> 6] = s;
    __syncthreads();
    if (t == 0)
        atomicAdd(out, (red[0] + red[1] + red[2] + red[3]) * (1.0f / (float)N_TOT));
}

extern "C" void kernel_launch(void* const* d_in, const int* in_sizes, int n_in,
                              void* d_out, int out_size, void* d_ws, size_t ws_size,
                              hipStream_t stream) {
    const float* p1 = (const float*)d_in[0];
    const float* p2 = (const float*)d_in[1];

    unsigned char* zf8 = (unsigned char*)d_ws;                          // 4 MB
    float* rowsum = (float*)((char*)d_ws + (size_t)N_TOT * D_DIM);      // 32 KB
    float* pos    = rowsum + N_TOT;                                     // 32 KB
    float* outp   = (float*)d_out;

    k_normalize<<<N_TOT / 4, 256, 0, stream>>>(p1, p2, zf8, rowsum, outp);
    k_gemm<<<NTILES, 256, 0, stream>>>(zf8, rowsum, pos);
    k_finalize<<<N_TOT / 256, 256, 0, stream>>>(rowsum, pos, outp);
}